// Round 1
// baseline (230.623 us; speedup 1.0000x reference)
//
#include <hip/hip_runtime.h>

#define EPS 1e-8f

// One block per output row (b, n). Block = 256 threads, each thread computes
// 4 consecutive m's. With NC=3, all of D/A/X is recomputed from registers:
//   D = ||C[b,n]||^2 + ||C[b,m]||^2 - 2<C[b,n],C[b,m]>
//   A = exp(-sigma^2 * D);  X = exp(-A) * mask;  out = X / (rowsum(X)+EPS)
__global__ __launch_bounds__(256) void gaussian_rownorm_kernel(
    const float* __restrict__ C,        // [B, N, 3]
    const float* __restrict__ masks,    // [B, N, N]
    const float* __restrict__ inv_sigma,// [1]
    float* __restrict__ out,            // [B, N, N]
    int N)
{
    const int row = blockIdx.x;         // row = b*N + n
    const int b   = row / N;
    const int n   = row - b * N;
    const int t   = threadIdx.x;

    const float s  = inv_sigma[0];
    const float s2 = s * s;

    // C for this batch; this 12 KB region is shared by all N blocks of the
    // batch -> L1/L2 resident, negligible HBM traffic.
    const float* __restrict__ Cb = C + (size_t)b * N * 3;

    // Query point C[b,n,:] (uniform across block; broadcast through cache).
    const float cn0 = Cb[n * 3 + 0];
    const float cn1 = Cb[n * 3 + 1];
    const float cn2 = Cb[n * 3 + 2];
    const float sqn = cn0 * cn0 + cn1 * cn1 + cn2 * cn2;

    // This thread's 4 neighbor points: C[b, m0..m0+3, :] = 12 floats = 48 B,
    // 16B-aligned (48*t), loaded as 3x float4.
    const int m0 = t * 4;
    const float4* __restrict__ cm = (const float4*)(Cb + (size_t)m0 * 3);
    const float4 ca = cm[0];   // m0:   ca.x ca.y ca.z | m1: ca.w ...
    const float4 cb4 = cm[1];  // m1:   cb4.x cb4.y    | m2: cb4.z cb4.w
    const float4 cc = cm[2];   // m2:   cc.x           | m3: cc.y cc.z cc.w

    const size_t rowbase = (size_t)row * N;
    const float4 mk = *(const float4*)(masks + rowbase + m0);

    #define CALC(c0, c1, c2, mval)                                  \
        ({                                                          \
            float _sqm = (c0)*(c0) + (c1)*(c1) + (c2)*(c2);         \
            float _dot = cn0*(c0) + cn1*(c1) + cn2*(c2);            \
            float _D   = sqn + _sqm - 2.0f * _dot;                  \
            float _A   = expf(-s2 * _D);                            \
            expf(-_A) * (mval);                                     \
        })

    const float x0 = CALC(ca.x,  ca.y,  ca.z,  mk.x);
    const float x1 = CALC(ca.w,  cb4.x, cb4.y, mk.y);
    const float x2 = CALC(cb4.z, cb4.w, cc.x,  mk.z);
    const float x3 = CALC(cc.y,  cc.z,  cc.w,  mk.w);
    #undef CALC

    // Row-sum reduction: per-thread partial -> wave64 butterfly -> LDS.
    float psum = (x0 + x1) + (x2 + x3);
    #pragma unroll
    for (int off = 32; off > 0; off >>= 1)
        psum += __shfl_xor(psum, off, 64);

    __shared__ float wsum[8];
    const int wid = t >> 6;
    if ((t & 63) == 0) wsum[wid] = psum;
    __syncthreads();

    const int nwaves = blockDim.x >> 6;
    float total = 0.0f;
    #pragma unroll
    for (int w = 0; w < 4; ++w)
        if (w < nwaves) total += wsum[w];

    const float r = 1.0f / (total + EPS);

    float4 o;
    o.x = x0 * r; o.y = x1 * r; o.z = x2 * r; o.w = x3 * r;
    *(float4*)(out + rowbase + m0) = o;
}

extern "C" void kernel_launch(void* const* d_in, const int* in_sizes, int n_in,
                              void* d_out, int out_size, void* d_ws, size_t ws_size,
                              hipStream_t stream) {
    const float* C         = (const float*)d_in[0];  // [B, N, 3]
    const float* masks     = (const float*)d_in[1];  // [B, N, N]
    const float* inv_sigma = (const float*)d_in[2];  // [1]
    float* out             = (float*)d_out;          // [B, N, N]

    // N = out_size*3 / in_sizes[0]  (out = B*N*N, C = B*N*3)
    const long long N_ll = (long long)out_size * 3LL / (long long)in_sizes[0];
    const int N = (int)N_ll;           // 1024 for the bench shape
    const int B = in_sizes[0] / (3 * N);

    const int block = N / 4;           // 256 threads for N=1024
    const int grid  = B * N;           // one block per output row

    gaussian_rownorm_kernel<<<grid, block, 0, stream>>>(C, masks, inv_sigma, out, N);
}